// Round 14
// baseline (245.280 us; speedup 1.0000x reference)
//
#include <hip/hip_runtime.h>
#include <type_traits>
#include <utility>

typedef unsigned short u16;
typedef unsigned int u32;
typedef short short8 __attribute__((ext_vector_type(8)));
typedef short s16x4 __attribute__((ext_vector_type(4)));
typedef __bf16 bf16x8 __attribute__((ext_vector_type(8)));
typedef float floatx4 __attribute__((ext_vector_type(4)));

// ---- MFMA wrapper robust to either builtin signature (short8 vs v8bf16) ----
template <typename V, typename = void> struct MfmaTakes : std::false_type {};
template <typename V>
struct MfmaTakes<V, std::void_t<decltype(__builtin_amdgcn_mfma_f32_16x16x32_bf16(
    std::declval<V>(), std::declval<V>(), std::declval<floatx4>(), 0, 0, 0))>>
    : std::true_type {};

template <typename V>
__device__ __forceinline__ floatx4 mfma_impl(V a, V b, floatx4 c, std::true_type) {
  return __builtin_amdgcn_mfma_f32_16x16x32_bf16(a, b, c, 0, 0, 0);
}
template <typename V>
__device__ __forceinline__ floatx4 mfma_impl(V a, V b, floatx4 c, std::false_type) {
  return __builtin_amdgcn_mfma_f32_16x16x32_bf16(
      __builtin_bit_cast(bf16x8, a), __builtin_bit_cast(bf16x8, b), c, 0, 0, 0);
}
__device__ __forceinline__ floatx4 MFMA16(short8 a, short8 b, floatx4 c) {
  return mfma_impl<short8>(a, b, c, MfmaTakes<short8>{});
}

// ---- K=16 MFMA: PV consumes P packed registers directly (no LDS round-trip).
__device__ __forceinline__ floatx4 MFMAK16(s16x4 a, s16x4 b, floatx4 c) {
  return __builtin_amdgcn_mfma_f32_16x16x16bf16_1k(a, b, c, 0, 0, 0);
}

// exp2 via BUILTIN only (v11 lesson: raw asm v_exp_f32 = TRANS-op hazard the
// compiler can't see -> stale-register reads -> wrong values).
#if defined(__has_builtin)
#if __has_builtin(__builtin_amdgcn_exp2f)
#define EXP2(x) __builtin_amdgcn_exp2f(x)
#else
#define EXP2(x) exp2f(x)
#endif
#else
#define EXP2(x) exp2f(x)
#endif

__device__ __forceinline__ u16 f2bf(float f) {
  union { float f; unsigned u; } x; x.f = f;
  unsigned r = (x.u + 0x7fffu + ((x.u >> 16) & 1u)) >> 16;
  return (u16)r;
}
__device__ __forceinline__ float bf2f(u16 v) {
  union { unsigned u; float f; } x; x.u = ((unsigned)v) << 16; return x.f;
}
__device__ __forceinline__ u32 packbf(float lo, float hi) {  // truncation pack (P)
  return (__float_as_uint(hi) & 0xffff0000u) | (__float_as_uint(lo) >> 16);
}
__device__ __forceinline__ u32 pack2bf(float lo, float hi) {  // round-nearest pack
  return ((u32)f2bf(hi) << 16) | (u32)f2bf(lo);
}

// ---- async global->LDS staging (16B/lane), fallback to vector copy ----
#if defined(__has_builtin)
#if __has_builtin(__builtin_amdgcn_global_load_lds)
#define HAS_GLLDS 1
#endif
#endif
__device__ __forceinline__ void stage16(const u16* g, u16* lbase, int lane) {
#ifdef HAS_GLLDS
  __builtin_amdgcn_global_load_lds(
      (__attribute__((address_space(1))) void*)(g),
      (__attribute__((address_space(3))) void*)(lbase), 16, 0, 0);
#else
  *(uint4*)(lbase + lane * 8) = *(const uint4*)g;
#endif
}

// attention scale folded with log2(e) so softmax exp is a bare v_exp_f32:
// p = exp(s*0.125) = exp2(s*0.125*log2e)
#define QSCALE 0.18033688011112042f

// ---------------- prep: x->bf16, concat W->bf16, out_w->bf16, lambda weights
// grid-stride (G11): 2304 blocks x 4 iterations instead of 9216 one-shot
// workgroups -> lower dispatch overhead, identical memory pattern.
__global__ __launch_bounds__(256) void prep_kernel(
    const float* __restrict__ x, const float* __restrict__ qw,
    const float* __restrict__ kw, const float* __restrict__ vw,
    const float* __restrict__ outw, const float* __restrict__ lam,
    u16* __restrict__ xb, u16* __restrict__ wcat, u16* __restrict__ outwb,
    float* __restrict__ lwbuf) {
  const size_t total = 2359296;  // 524288 + 1572864 + 262144
  const size_t stride = (size_t)gridDim.x * 256;
  for (size_t gid = (size_t)blockIdx.x * 256 + threadIdx.x; gid < total;
       gid += stride) {
    if (gid == 0) {
      float s0 = 1.f / (1.f + expf(-lam[0]));
      float s1 = 1.f / (1.f + expf(-lam[1]));
      float s2 = 1.f / (1.f + expf(-lam[2]));
      float mean = (s0 + s1 + s2) * (1.f / 3.f);
      float d0 = s0 - mean, d1 = s1 - mean, d2 = s2 - mean;
      float var = (d0 * d0 + d1 * d1 + d2 * d2) * (1.f / 3.f);
      float r = rsqrtf(var + 1e-5f);
      lwbuf[0] = d0 * r; lwbuf[1] = d1 * r; lwbuf[2] = d2 * r;
    }
    if (gid < 524288) {
      float4 v = ((const float4*)x)[gid];
      ushort4 o; o.x = f2bf(v.x); o.y = f2bf(v.y); o.z = f2bf(v.z); o.w = f2bf(v.w);
      ((ushort4*)xb)[gid] = o;
    } else {
      size_t g2 = gid - 524288;
      if (g2 < 1572864) {  // wcat rows: [layer][q(1024)|k(512)|v(512)] x 1024 cols
        int col4 = (int)(g2 & 255);
        int n = (int)(g2 >> 8);
        int layer = n >> 11, r = n & 2047;
        const float* srcrow;
        if (r < 1024) srcrow = qw + ((size_t)(layer * 1024 + r) << 10);
        else if (r < 1536) srcrow = kw + ((size_t)(layer * 512 + (r - 1024)) << 10);
        else srcrow = vw + ((size_t)(layer * 512 + (r - 1536)) << 10);
        float4 v = ((const float4*)srcrow)[col4];
        ushort4 o; o.x = f2bf(v.x); o.y = f2bf(v.y); o.z = f2bf(v.z); o.w = f2bf(v.w);
        ((ushort4*)wcat)[g2] = o;
      } else {
        size_t g3 = g2 - 1572864;
        float4 v = ((const float4*)outw)[g3];
        ushort4 o; o.x = f2bf(v.x); o.y = f2bf(v.y); o.z = f2bf(v.z); o.w = f2bf(v.w);
        ((ushort4*)outwb)[g3] = o;
      }
    }
  }
}

// ---------------- fused QKV GEMM: 128x128 tile + in-epilogue RoPE/scatter.
__global__ __launch_bounds__(256) void gemm_qkv(
    const u16* __restrict__ A, const u16* __restrict__ Bw,
    const float* __restrict__ cosb, const float* __restrict__ sinb,
    u16* __restrict__ qr, u16* __restrict__ kr, u16* __restrict__ vt) {
  __shared__ u16 As[128][64];
  __shared__ u16 Bs[128][64];
  const unsigned flat = blockIdx.x;
  const int bm = (flat >> 3) & 15;
  const int bn = ((flat >> 7) << 3) + (flat & 7);  // same bn -> same XCD
  const int tid = threadIdx.x;
  const int wave = tid >> 6, lane = tid & 63;
  const int quad = lane >> 4, l16 = lane & 15;
  const int wm = wave & 1, wn = wave >> 1;
  const int srow = lane >> 3, skc = (lane & 7) * 8;
  floatx4 acc[4][4];
#pragma unroll
  for (int i = 0; i < 4; i++)
#pragma unroll
    for (int j = 0; j < 4; j++) { acc[i][j][0] = 0.f; acc[i][j][1] = 0.f; acc[i][j][2] = 0.f; acc[i][j][3] = 0.f; }
  const u16* Abase = A + (size_t)(bm * 128) * 1024;
  const u16* Bbase = Bw + (size_t)(bn * 128) * 1024;
  for (int k0 = 0; k0 < 1024; k0 += 64) {
    __syncthreads();
#pragma unroll
    for (int i = 0; i < 4; i++) {
      int ch = wave * 4 + i;
      stage16(Abase + (size_t)(ch * 8 + srow) * 1024 + k0 + skc, &As[ch * 8][0], lane);
      stage16(Bbase + (size_t)(ch * 8 + srow) * 1024 + k0 + skc, &Bs[ch * 8][0], lane);
    }
    __syncthreads();
#pragma unroll
    for (int kf = 0; kf < 2; kf++) {
      short8 af[4], bf[4];
#pragma unroll
      for (int mi = 0; mi < 4; mi++)
        af[mi] = *(const short8*)(&As[wm * 64 + mi * 16 + l16][kf * 32 + quad * 8]);
#pragma unroll
      for (int ni = 0; ni < 4; ni++)
        bf[ni] = *(const short8*)(&Bs[wn * 64 + ni * 16 + l16][kf * 32 + quad * 8]);
#pragma unroll
      for (int mi = 0; mi < 4; mi++)
#pragma unroll
        for (int ni = 0; ni < 4; ni++)
          acc[mi][ni] = MFMA16(af[mi], bf[ni], acc[mi][ni]);
    }
  }
  // ---- fused epilogue (wave-uniform branches) ----
  const int f0 = bn * 128 + wn * 64;   // wave's feature base
  const int lay = f0 >> 11;
  const int r0 = f0 & 2047;            // multiple of 64 -> type/head uniform
  const int mrow0 = bm * 128 + wm * 64;
  if (r0 < 1024) {                     // ---- Q: RoPE(pos=t) * scale*log2e
    const int h = r0 >> 6;
#pragma unroll
    for (int mi = 0; mi < 4; mi++)
#pragma unroll
      for (int rr = 0; rr < 4; rr++) {
        int m = mrow0 + mi * 16 + quad * 4 + rr;
        int b = m >> 10, t = m & 1023;
        const float* cp = cosb + (size_t)t * 32;
        const float* sp = sinb + (size_t)t * 32;
        float c0 = cp[l16], s0 = sp[l16];
        float c1 = cp[16 + l16], s1 = sp[16 + l16];
        float x10 = acc[mi][0][rr], x20 = acc[mi][2][rr];
        float x11 = acc[mi][1][rr], x21 = acc[mi][3][rr];
        u16* row = qr + ((((size_t)lay * 2 + b) * 16 + h) * 1024 + t) * 64;
        row[l16]      = f2bf((x10 * c0 - x20 * s0) * QSCALE);
        row[16 + l16] = f2bf((x11 * c1 - x21 * s1) * QSCALE);
        row[32 + l16] = f2bf((x20 * c0 + x10 * s0) * QSCALE);
        row[48 + l16] = f2bf((x21 * c1 + x11 * s1) * QSCALE);
      }
  } else if (r0 < 1536) {              // ---- K: RoPE(pos=lay*1024+t)
    const int hk = (r0 - 1024) >> 6;
#pragma unroll
    for (int mi = 0; mi < 4; mi++)
#pragma unroll
      for (int rr = 0; rr < 4; rr++) {
        int m = mrow0 + mi * 16 + quad * 4 + rr;
        int b = m >> 10, t = m & 1023;
        int pos = lay * 1024 + t;
        const float* cp = cosb + (size_t)pos * 32;
        const float* sp = sinb + (size_t)pos * 32;
        float c0 = cp[l16], s0 = sp[l16];
        float c1 = cp[16 + l16], s1 = sp[16 + l16];
        float x10 = acc[mi][0][rr], x20 = acc[mi][2][rr];
        float x11 = acc[mi][1][rr], x21 = acc[mi][3][rr];
        u16* row = kr + (((size_t)(b * 8 + hk)) * 3072 + pos) * 64;
        row[l16]      = f2bf(x10 * c0 - x20 * s0);
        row[16 + l16] = f2bf(x11 * c1 - x21 * s1);
        row[32 + l16] = f2bf(x20 * c0 + x10 * s0);
        row[48 + l16] = f2bf(x21 * c1 + x11 * s1);
      }
  } else {                             // ---- V: transposed store [d][pos], 8B packs
    const int hv = (r0 - 1536) >> 6;
#pragma unroll
    for (int mi = 0; mi < 4; mi++) {
      int m0 = mrow0 + mi * 16 + quad * 4;
      int b = m0 >> 10;
      int pos0 = lay * 1024 + (m0 & 1023);
      u16* colbase = vt + ((size_t)(b * 8 + hv) * 64) * 3072 + pos0;
#pragma unroll
      for (int ni = 0; ni < 4; ni++) {
        int d = ni * 16 + l16;
        uint2 st;
        st.x = pack2bf(acc[mi][ni][0], acc[mi][ni][1]);
        st.y = pack2bf(acc[mi][ni][2], acc[mi][ni][3]);
        *(uint2*)(colbase + (size_t)d * 3072) = st;
      }
    }
  }
}

// ---------------- out-projection GEMM: 64x64 tile, double-buffered
// (proven in v14: ~5-6us total win; single barrier per K-step).
__global__ __launch_bounds__(256) void gemm_bt(
    const u16* __restrict__ A, const u16* __restrict__ Bw,
    float* __restrict__ C, int N, int K) {
  __shared__ u16 As[2][64][72];
  __shared__ u16 Bs[2][64][72];
  const int bm = blockIdx.x, bn = blockIdx.y;
  const int tid = threadIdx.x;
  const int wave = tid >> 6, lane = tid & 63;
  const int quad = lane >> 4, l16 = lane & 15;
  const int lr = tid >> 2, lc = (tid & 3) << 4;
  floatx4 acc[4];
#pragma unroll
  for (int i = 0; i < 4; i++) { acc[i][0] = 0.f; acc[i][1] = 0.f; acc[i][2] = 0.f; acc[i][3] = 0.f; }
  const u16* Arow = A + (size_t)(bm * 64 + lr) * K;
  const u16* Brow = Bw + (size_t)(bn * 64 + lr) * K;
  // prologue: tile 0 -> buf0; prefetch tile 1 into regs
  uint4 ra0 = *(const uint4*)(Arow + lc);
  uint4 ra1 = *(const uint4*)(Arow + lc + 8);
  uint4 rb0 = *(const uint4*)(Brow + lc);
  uint4 rb1 = *(const uint4*)(Brow + lc + 8);
  *(uint4*)(&As[0][lr][lc])     = ra0;
  *(uint4*)(&As[0][lr][lc + 8]) = ra1;
  *(uint4*)(&Bs[0][lr][lc])     = rb0;
  *(uint4*)(&Bs[0][lr][lc + 8]) = rb1;
  if (64 < K) {
    ra0 = *(const uint4*)(Arow + 64 + lc);
    ra1 = *(const uint4*)(Arow + 64 + lc + 8);
    rb0 = *(const uint4*)(Brow + 64 + lc);
    rb1 = *(const uint4*)(Brow + 64 + lc + 8);
  }
  int p = 0;
  for (int k0 = 0; k0 < K; k0 += 64, p ^= 1) {
    __syncthreads();   // buf[p] writes visible; prior reads of buf[p^1] done
    if (k0 + 64 < K) {  // write-late: next tile -> other buffer
      *(uint4*)(&As[p ^ 1][lr][lc])     = ra0;
      *(uint4*)(&As[p ^ 1][lr][lc + 8]) = ra1;
      *(uint4*)(&Bs[p ^ 1][lr][lc])     = rb0;
      *(uint4*)(&Bs[p ^ 1][lr][lc + 8]) = rb1;
      if (k0 + 128 < K) {
        ra0 = *(const uint4*)(Arow + k0 + 128 + lc);
        ra1 = *(const uint4*)(Arow + k0 + 128 + lc + 8);
        rb0 = *(const uint4*)(Brow + k0 + 128 + lc);
        rb1 = *(const uint4*)(Brow + k0 + 128 + lc + 8);
      }
    }
    const int mrow = wave * 16 + l16;
    short8 a0 = *(const short8*)(&As[p][mrow][quad * 8]);
    short8 a1 = *(const short8*)(&As[p][mrow][32 + quad * 8]);
#pragma unroll
    for (int ns = 0; ns < 4; ns++) {
      short8 b0 = *(const short8*)(&Bs[p][ns * 16 + l16][quad * 8]);
      short8 b1 = *(const short8*)(&Bs[p][ns * 16 + l16][32 + quad * 8]);
      acc[ns] = MFMA16(a0, b0, acc[ns]);
      acc[ns] = MFMA16(a1, b1, acc[ns]);
    }
  }
#pragma unroll
  for (int ns = 0; ns < 4; ns++)
#pragma unroll
    for (int r = 0; r < 4; r++) {
      int row = bm * 64 + wave * 16 + quad * 4 + r;
      int col = bn * 64 + ns * 16 + l16;
      C[(size_t)row * N + col] = acc[ns][r];
    }
}

// ---------------- attention v16: v8/v15 structure (measured optimum) +
// ISOLATED T5 s_setprio around the pure-MFMA PV cluster. v12 bundled setprio
// with KVBLK=64 (confounded); this is the clean A/B on the best structure.
__global__ __launch_bounds__(512) void attn_v16(
    const u16* __restrict__ qr, const u16* __restrict__ kr,
    const u16* __restrict__ vt, u16* __restrict__ obS,
    float* __restrict__ lbufp) {
  // layout (u16 units): Kt[2][32][72] at 0 (4608) | Vtt[2][64][40] at 4608 (5120)
  // epilogue: float scratch wave*320 floats aliased at base (after barrier)
  __shared__ __align__(16) u16 smem[9728];   // 19456 B
  u16* KtB = smem;
  u16* VtB = smem + 4608;
  const unsigned flat = blockIdx.x;
  const int xcd = (int)(flat & 7);
  const int m = (int)(flat >> 3);       // 0..95
  const int qtile = m / 12;             // 0..7 (non-pow2 scatter over CUs)
  const int g = m - qtile * 12;         // 0..11
  const int pid = g * 8 + xcd;          // 0..95 = (z,b,j); low bits keep XCD L2 locality
  const int z = pid >> 4;
  const int rb = pid & 15;
  const int b = rb >> 3, j = rb & 7;    // j = kv head (hk)
  const int lay = (z == 5) ? 0 : ((z == 0 || z == 4) ? 1 : 2);
  const int n = lay * 32 + qtile * 4 + 4;   // total 32-key tiles for this (lay,qtile)
  int kt0, kt1;
  if (lay == 0) { kt0 = 0; kt1 = n; }
  else if (lay == 1) { int hf = n >> 1; kt0 = (z == 0) ? 0 : hf; kt1 = (z == 0) ? hf : n; }
  else {
    int t1 = n / 3, t2 = (2 * n) / 3;
    kt0 = (z == 1) ? 0 : ((z == 2) ? t1 : t2);
    kt1 = (z == 1) ? t1 : ((z == 2) ? t2 : n);
  }
  const int maskkt = lay * 32 + qtile * 4;
  const int tid = threadIdx.x, wave = tid >> 6, lane = tid & 63;
  const int quad = lane >> 4, l16 = lane & 15;
  const int hw = wave >> 2, wq = wave & 3;   // head-half, wave-within-head
  const int h = j * 2 + hw;
  const int qeffbase = lay * 1024 + qtile * 128 + wq * 32;
  const u16* qpb = qr + ((((size_t)lay * 2 + b) * 16 + h) * 1024
                         + qtile * 128 + wq * 32 + l16) * 64 + quad * 8;
  short8 qf[2][2];
  qf[0][0] = *(const short8*)(qpb);
  qf[0][1] = *(const short8*)(qpb + 32);
  qf[1][0] = *(const short8*)(qpb + 1024);
  qf[1][1] = *(const short8*)(qpb + 1056);
  const s16x4 ones4 = {16256, 16256, 16256, 16256};
  floatx4 oacc[2][4];
#pragma unroll
  for (int nt = 0; nt < 2; nt++)
#pragma unroll
    for (int dt = 0; dt < 4; dt++) { oacc[nt][dt][0] = 0.f; oacc[nt][dt][1] = 0.f; oacc[nt][dt][2] = 0.f; oacc[nt][dt][3] = 0.f; }
  floatx4 lacc[2];
  lacc[0][0] = 0.f; lacc[0][1] = 0.f; lacc[0][2] = 0.f; lacc[0][3] = 0.f;
  lacc[1] = lacc[0];
  // staging: waves 0-3 (256 lanes) stage K tile (32x64), waves 4-7 stage V (64x32)
  const bool isK = (tid < 256);
  const int t2i = tid & 255;
  const int ksr = t2i >> 3, ksc = (t2i & 7) * 8;   // K: 8 lanes/row x 16B
  const int vdr = t2i >> 2, vdc = (t2i & 3) * 8;   // V: 4 lanes/row x 16B
  const u16* gp = isK
      ? kr + ((size_t)(b * 8 + j) * 3072 + kt0 * 32 + ksr) * 64 + ksc
      : vt + ((size_t)(b * 8 + j) * 64 + vdr) * 3072 + kt0 * 32 + vdc;
  const size_t gstep = isK ? 2048 : 32;
  u16* ld0 = isK ? &KtB[ksr * 72 + ksc] : &VtB[vdr * 40 + vdc];
  u16* ld1 = isK ? &KtB[2304 + ksr * 72 + ksc] : &VtB[2560 + vdr * 40 + vdc];
  // prologue: tile kt0 -> buf0; prefetch tile kt0+1 into regs
  uint4 gA = *(const uint4*)gp;
  *(uint4*)ld0 = gA;
  gp += gstep;
  if (kt0 + 1 < kt1) gA = *(const uint4*)gp;
  for (int kt = kt0; kt < kt1; kt++) {
    const int p = (kt - kt0) & 1;
    __syncthreads();   // buf[p] writes visible; prior reads of buf[p^1] done
    if (kt + 1 < kt1) {   // write-late: next tile -> other buffer, overlaps compute
      *(uint4*)(p ? ld0 : ld1) = gA;
      gp += gstep;
      if (kt + 2 < kt1) gA = *(const uint4*)gp;
    }
    const bool needmask = (kt >= maskkt);
    const u16* Ktp = &KtB[p * 2304];
    const u16* Vtp = &VtB[p * 2560];
    uint2 pk[2][2];  // [mt][nt], 4 bf16 each = keys quad*4..+3 of 16-key group mt
#pragma unroll
    for (int mt = 0; mt < 2; mt++) {
      short8 kfa = *(const short8*)(&Ktp[(mt * 16 + l16) * 72 + quad * 8]);
      short8 kfb = *(const short8*)(&Ktp[(mt * 16 + l16) * 72 + 32 + quad * 8]);
      const int keyb = kt * 32 + mt * 16 + quad * 4;
#pragma unroll
      for (int nt = 0; nt < 2; nt++) {
        floatx4 s; s[0] = 0.f; s[1] = 0.f; s[2] = 0.f; s[3] = 0.f;
        s = MFMA16(kfa, qf[nt][0], s);
        s = MFMA16(kfb, qf[nt][1], s);
        float p0 = EXP2(s[0]), p1 = EXP2(s[1]);
        float p2 = EXP2(s[2]), p3 = EXP2(s[3]);
        if (needmask) {
          int qpos = qeffbase + nt * 16 + l16;
          if (keyb + 0 > qpos) p0 = 0.f;
          if (keyb + 1 > qpos) p1 = 0.f;
          if (keyb + 2 > qpos) p2 = 0.f;
          if (keyb + 3 > qpos) p3 = 0.f;
        }
        pk[mt][nt].x = packbf(p0, p1);
        pk[mt][nt].y = packbf(p2, p3);
      }
    }
    s16x4 p0f0 = __builtin_bit_cast(s16x4, pk[0][0]);
    s16x4 p1f0 = __builtin_bit_cast(s16x4, pk[1][0]);
    s16x4 p0f1 = __builtin_bit_cast(s16x4, pk[0][1]);
    s16x4 p1f1 = __builtin_bit_cast(s16x4, pk[1][1]);
    __builtin_amdgcn_s_setprio(1);   // T5: favor this wave through the MFMA cluster
    lacc[0] = MFMAK16(ones4, p0f0, lacc[0]);
    lacc[0] = MFMAK16(ones4, p1f0, lacc[0]);
    lacc[1] = MFMAK16(ones4, p0f1, lacc[1]);
    lacc[1] = MFMAK16(ones4, p1f1, lacc[1]);
    // V fragments loaded per-dt: a[j] = V^T[d][k=quad*4+j]
#pragma unroll
    for (int dt = 0; dt < 4; dt++) {
      s16x4 v0 = *(const s16x4*)(&Vtp[(dt * 16 + l16) * 40 + quad * 4]);
      s16x4 v1 = *(const s16x4*)(&Vtp[(dt * 16 + l16) * 40 + 16 + quad * 4]);
      oacc[0][dt] = MFMAK16(v0, p0f0, oacc[0][dt]);
      oacc[0][dt] = MFMAK16(v1, p1f0, oacc[0][dt]);
      oacc[1][dt] = MFMAK16(v0, p0f1, oacc[1][dt]);
      oacc[1][dt] = MFMAK16(v1, p1f1, oacc[1][dt]);
    }
    __builtin_amdgcn_s_setprio(0);
  }
  // epilogue: O^T (d,t) -> row-major [t][d] via per-wave scratch ALIASED on K/V
  __syncthreads();   // all waves done reading Kt/Vtt before scratch overwrite
  float* Pf = (float*)smem + wave * 320;   // 16x20 floats per wave
  const int tt = lane >> 2, dd = (lane & 3) << 2;
#pragma unroll
  for (int nt = 0; nt < 2; nt++) {
    int t = qtile * 128 + wq * 32 + nt * 16 + l16;
    if (quad == 0)
      lbufp[((size_t)z * 2048 + b * 1024 + t) * 16 + h] = lacc[nt][0];
    int t2 = qtile * 128 + wq * 32 + nt * 16 + tt;
    u16* orow = obS + ((size_t)(z * 2 + b) * 1024 + t2) * 1024 + h * 64 + dd;
#pragma unroll
    for (int dt = 0; dt < 4; dt++) {
      *(floatx4*)(&Pf[l16 * 20 + quad * 4]) = oacc[nt][dt];   // [t][d] tile
      floatx4 val = *(const floatx4*)(&Pf[tt * 20 + dd]);     // wave in-order
      uint2 st; st.x = pack2bf(val[0], val[1]); st.y = pack2bf(val[2], val[3]);
      *(uint2*)(orow + dt * 16) = st;
    }
  }
}

// ---------------- fused norm: merged 3-layer reduction (v2, measured-neutral
// but fewer barriers; kept).
__device__ __forceinline__ void block_sum3(float& v0, float& v1, float& v2,
                                           float* red) {
#pragma unroll
  for (int s = 32; s >= 1; s >>= 1) {
    v0 += __shfl_xor(v0, s);
    v1 += __shfl_xor(v1, s);
    v2 += __shfl_xor(v2, s);
  }
  __syncthreads();
  if ((threadIdx.x & 63) == 0) {
    int w = threadIdx.x >> 6;
    red[w * 3 + 0] = v0; red[w * 3 + 1] = v1; red[w * 3 + 2] = v2;
  }
  __syncthreads();
  v0 = red[0] + red[3] + red[6] + red[9];
  v1 = red[1] + red[4] + red[7] + red[10];
  v2 = red[2] + red[5] + red[8] + red[11];
}

__device__ __forceinline__ float block_sum(float v, float* red) {
  v += __shfl_xor(v, 32); v += __shfl_xor(v, 16); v += __shfl_xor(v, 8);
  v += __shfl_xor(v, 4);  v += __shfl_xor(v, 2);  v += __shfl_xor(v, 1);
  __syncthreads();
  if ((threadIdx.x & 63) == 0) red[threadIdx.x >> 6] = v;
  __syncthreads();
  return red[0] + red[1] + red[2] + red[3];
}

__device__ __forceinline__ void addslot(const u16* __restrict__ obS,
    const float* __restrict__ lbufp, int row, int tid, int z,
    float o[4], float& ls) {
  uint2 v = ((const uint2*)(obS + ((size_t)z * 2048 + row) * 1024))[tid];
  o[0] += bf2f((u16)(v.x & 0xffff)); o[1] += bf2f((u16)(v.x >> 16));
  o[2] += bf2f((u16)(v.y & 0xffff)); o[3] += bf2f((u16)(v.y >> 16));
  ls += lbufp[((size_t)z * 2048 + row) * 16 + (tid >> 4)];
}

__global__ __launch_bounds__(256) void fused_norm(
    const u16* __restrict__ obS, const float* __restrict__ lbufp,
    const float* __restrict__ x, const float* __restrict__ lnw,
    const float* __restrict__ lwbuf, const float* __restrict__ flnw,
    const float* __restrict__ alphap, u16* __restrict__ y) {
  __shared__ float red[12];
  const int row = blockIdx.x, tid = threadIdx.x;  // row = b*1024+t
  // layer -> slots: l0 = {5}, l1 = {0,4}, l2 = {1,2,3}
  float q0[4] = {0.f, 0.f, 0.f, 0.f};
  float q1[4] = {0.f, 0.f, 0.f, 0.f};
  float q2[4] = {0.f, 0.f, 0.f, 0.f};
  float ls0 = 0.f, ls1 = 0.f, ls2 = 0.f;
  addslot(obS, lbufp, row, tid, 5, q0, ls0);
  addslot(obS, lbufp, row, tid, 0, q1, ls1);
  addslot(obS, lbufp, row, tid, 4, q1, ls1);
  addslot(obS, lbufp, row, tid, 1, q2, ls2);
  addslot(obS, lbufp, row, tid, 2, q2, ls2);
  addslot(obS, lbufp, row, tid, 3, q2, ls2);
  const float i0 = 1.f / ls0, i1 = 1.f / ls1, i2 = 1.f / ls2;
  float u0[4], u1[4], u2[4];
#pragma unroll
  for (int k = 0; k < 4; k++) { u0[k] = q0[k] * i0; u1[k] = q1[k] * i1; u2[k] = q2[k] * i2; }
  float ss0 = u0[0]*u0[0] + u0[1]*u0[1] + u0[2]*u0[2] + u0[3]*u0[3];
  float ss1 = u1[0]*u1[0] + u1[1]*u1[1] + u1[2]*u1[2] + u1[3]*u1[3];
  float ss2 = u2[0]*u2[0] + u2[1]*u2[1] + u2[2]*u2[2] + u2[3]*u2[3];
  block_sum3(ss0, ss1, ss2, red);
  const float r0 = rsqrtf(ss0 * (1.f / 1024.f) + 1e-5f) * lwbuf[0];
  const float r1 = rsqrtf(ss1 * (1.f / 1024.f) + 1e-5f) * lwbuf[1];
  const float r2 = rsqrtf(ss2 * (1.f / 1024.f) + 1e-5f) * lwbuf[2];
  float4 w0 = ((const float4*)(lnw))[tid];
  float4 w1 = ((const float4*)(lnw + 1024))[tid];
  float4 w2 = ((const float4*)(lnw + 2048))[tid];
  float a[4];
  a[0] = u0[0]*r0*w0.x + u1[0]*r1*w1.x + u2[0]*r2*w2.x;
  a[1] = u0[1]*r0*w0.y + u1[1]*r1*w1.y + u2[1]*r2*w2.y;
  a[2] = u0[2]*r0*w0.z + u1[2]*r1*w1.z + u2[2]*r2*w2.z;
  a[3] = u0[3]*r0*w0.w + u1[3]*r1*w1.w + u2[3]*r2*w2.w;
  const float aa = alphap[0];
  float4 xv = ((const float4*)(x + (size_t)row * 1024))[tid];
  float v0 = a[0] + aa * xv.x, v1 = a[1] + aa * xv.y;
  float v2 = a[2] + aa * xv.z, v3 = a[3] + aa * xv.w;
  float ss = v0 * v0 + v1 * v1 + v2 * v2 + v3 * v3;
  ss = block_sum(ss, red);
  float rstd = rsqrtf(ss * (1.f / 1024.f) + 1e-5f);
  float4 fw = ((const float4*)flnw)[tid];
  ushort4 o;
  o.x = f2bf(v0 * rstd * fw.x); o.y = f2bf(v1 * rstd * fw.y);
  o.z = f2bf(v2 * rstd * fw.z); o.w = f2bf(v3 * rstd * fw.w);
  ((ushort4*)(y + (size_t)row * 1024))[tid] = o;
}

extern "C" void kernel_launch(void* const* d_in, const int* in_sizes, int n_in,
                              void* d_out, int out_size, void* d_ws, size_t ws_size,
                              hipStream_t stream) {
  const float* x     = (const float*)d_in[0];
  const float* cosb  = (const float*)d_in[1];
  const float* sinb  = (const float*)d_in[2];
  const float* qw    = (const float*)d_in[3];
  const float* kw    = (const float*)d_in[4];
  const float* vw    = (const float*)d_in[5];
  const float* lnw   = (const float*)d_in[6];
  const float* lam   = (const float*)d_in[7];
  const float* outw  = (const float*)d_in[8];
  const float* flnw  = (const float*)d_in[9];
  const float* alphap= (const float*)d_in[10];
  float* out = (float*)d_out;
  char* ws = (char*)d_ws;
  // workspace (~57.4 MB). Region [0,24M) is time-shared:
  //   phase 1 (prep/gemm_qkv): xb [0,4M) + wcat [4M,16M)
  //   phase 2 (attn/fused_norm): obS [0,24M)  bf16 [z][b][t][h*64+d]
  u16*   xb    = (u16*)  (ws + 0);          //  4 MB
  u16*   wcat  = (u16*)  (ws + 4194304);    // 12 MB
  u16*   obS   = (u16*)  (ws + 0);          // 24 MB (phase 2)
  u16*   outwb = (u16*)  (ws + 25165824);   //  2 MB
  float* lwbuf = (float*)(ws + 27262976);   //  1 KB
  u16*   qr    = (u16*)  (ws + 27264000);   // 12 MB  [3][2][16][1024][64]
  u16*   kr    = (u16*)  (ws + 39846912);   //  6 MB  [2][8][3072][64]
  u16*   vt    = (u16*)  (ws + 46138368);   //  6 MB  [2][8][64][3072]
  float* lbufp = (float*)(ws + 52429824);   // 768 KB [6][2048][16]
  u16*   yb    = (u16*)  (ws + 53216256);   //  4 MB

  prep_kernel<<<2304, 256, 0, stream>>>(x, qw, kw, vw, outw, lam, xb, wcat, outwb, lwbuf);
  gemm_qkv<<<768, 256, 0, stream>>>(xb, wcat, cosb, sinb, qr, kr, vt);
  attn_v16<<<768, 512, 0, stream>>>(qr, kr, vt, obS, lbufp);
  fused_norm<<<2048, 256, 0, stream>>>(obS, lbufp, x, lnw, lwbuf, flnw, alphap, yb);
  gemm_bt<<<dim3(32, 16), 256, 0, stream>>>(yb, outwb, out, 1024, 1024);
}

// Round 15
// 240.050 us; speedup vs baseline: 1.0218x; 1.0218x over previous
//
#include <hip/hip_runtime.h>
#include <type_traits>
#include <utility>

typedef unsigned short u16;
typedef unsigned int u32;
typedef short short8 __attribute__((ext_vector_type(8)));
typedef short s16x4 __attribute__((ext_vector_type(4)));
typedef __bf16 bf16x8 __attribute__((ext_vector_type(8)));
typedef float floatx4 __attribute__((ext_vector_type(4)));

// ---- MFMA wrapper robust to either builtin signature (short8 vs v8bf16) ----
template <typename V, typename = void> struct MfmaTakes : std::false_type {};
template <typename V>
struct MfmaTakes<V, std::void_t<decltype(__builtin_amdgcn_mfma_f32_16x16x32_bf16(
    std::declval<V>(), std::declval<V>(), std::declval<floatx4>(), 0, 0, 0))>>
    : std::true_type {};

template <typename V>
__device__ __forceinline__ floatx4 mfma_impl(V a, V b, floatx4 c, std::true_type) {
  return __builtin_amdgcn_mfma_f32_16x16x32_bf16(a, b, c, 0, 0, 0);
}
template <typename V>
__device__ __forceinline__ floatx4 mfma_impl(V a, V b, floatx4 c, std::false_type) {
  return __builtin_amdgcn_mfma_f32_16x16x32_bf16(
      __builtin_bit_cast(bf16x8, a), __builtin_bit_cast(bf16x8, b), c, 0, 0, 0);
}
__device__ __forceinline__ floatx4 MFMA16(short8 a, short8 b, floatx4 c) {
  return mfma_impl<short8>(a, b, c, MfmaTakes<short8>{});
}

// ---- K=16 MFMA: PV consumes P packed registers directly (no LDS round-trip).
__device__ __forceinline__ floatx4 MFMAK16(s16x4 a, s16x4 b, floatx4 c) {
  return __builtin_amdgcn_mfma_f32_16x16x16bf16_1k(a, b, c, 0, 0, 0);
}

// exp2 via BUILTIN only (v11 lesson: raw asm v_exp_f32 = TRANS-op hazard the
// compiler can't see -> stale-register reads -> wrong values).
#if defined(__has_builtin)
#if __has_builtin(__builtin_amdgcn_exp2f)
#define EXP2(x) __builtin_amdgcn_exp2f(x)
#else
#define EXP2(x) exp2f(x)
#endif
#else
#define EXP2(x) exp2f(x)
#endif

__device__ __forceinline__ u16 f2bf(float f) {
  union { float f; unsigned u; } x; x.f = f;
  unsigned r = (x.u + 0x7fffu + ((x.u >> 16) & 1u)) >> 16;
  return (u16)r;
}
__device__ __forceinline__ float bf2f(u16 v) {
  union { unsigned u; float f; } x; x.u = ((unsigned)v) << 16; return x.f;
}
__device__ __forceinline__ u32 packbf(float lo, float hi) {  // truncation pack (P)
  return (__float_as_uint(hi) & 0xffff0000u) | (__float_as_uint(lo) >> 16);
}
__device__ __forceinline__ u32 pack2bf(float lo, float hi) {  // round-nearest pack
  return ((u32)f2bf(hi) << 16) | (u32)f2bf(lo);
}

// ---- async global->LDS staging (16B/lane), fallback to vector copy ----
#if defined(__has_builtin)
#if __has_builtin(__builtin_amdgcn_global_load_lds)
#define HAS_GLLDS 1
#endif
#endif
__device__ __forceinline__ void stage16(const u16* g, u16* lbase, int lane) {
#ifdef HAS_GLLDS
  __builtin_amdgcn_global_load_lds(
      (__attribute__((address_space(1))) void*)(g),
      (__attribute__((address_space(3))) void*)(lbase), 16, 0, 0);
#else
  *(uint4*)(lbase + lane * 8) = *(const uint4*)g;
#endif
}

// attention scale folded with log2(e) so softmax exp is a bare v_exp_f32:
// p = exp(s*0.125) = exp2(s*0.125*log2e)
#define QSCALE 0.18033688011112042f

// ---------------- prep: x->bf16, concat W->bf16, out_w->bf16, lambda weights
__global__ __launch_bounds__(256) void prep_kernel(
    const float* __restrict__ x, const float* __restrict__ qw,
    const float* __restrict__ kw, const float* __restrict__ vw,
    const float* __restrict__ outw, const float* __restrict__ lam,
    u16* __restrict__ xb, u16* __restrict__ wcat, u16* __restrict__ outwb,
    float* __restrict__ lwbuf) {
  size_t gid = (size_t)blockIdx.x * 256 + threadIdx.x;
  if (gid == 0) {
    float s0 = 1.f / (1.f + expf(-lam[0]));
    float s1 = 1.f / (1.f + expf(-lam[1]));
    float s2 = 1.f / (1.f + expf(-lam[2]));
    float mean = (s0 + s1 + s2) * (1.f / 3.f);
    float d0 = s0 - mean, d1 = s1 - mean, d2 = s2 - mean;
    float var = (d0 * d0 + d1 * d1 + d2 * d2) * (1.f / 3.f);
    float r = rsqrtf(var + 1e-5f);
    lwbuf[0] = d0 * r; lwbuf[1] = d1 * r; lwbuf[2] = d2 * r;
  }
  if (gid < 524288) {
    float4 v = ((const float4*)x)[gid];
    ushort4 o; o.x = f2bf(v.x); o.y = f2bf(v.y); o.z = f2bf(v.z); o.w = f2bf(v.w);
    ((ushort4*)xb)[gid] = o;
    return;
  }
  size_t g2 = gid - 524288;
  if (g2 < 1572864) {  // wcat rows: [layer][q(1024)|k(512)|v(512)] x 1024 cols
    int col4 = (int)(g2 & 255);
    int n = (int)(g2 >> 8);
    int layer = n >> 11, r = n & 2047;
    const float* srcrow;
    if (r < 1024) srcrow = qw + ((size_t)(layer * 1024 + r) << 10);
    else if (r < 1536) srcrow = kw + ((size_t)(layer * 512 + (r - 1024)) << 10);
    else srcrow = vw + ((size_t)(layer * 512 + (r - 1536)) << 10);
    float4 v = ((const float4*)srcrow)[col4];
    ushort4 o; o.x = f2bf(v.x); o.y = f2bf(v.y); o.z = f2bf(v.z); o.w = f2bf(v.w);
    ((ushort4*)wcat)[g2] = o;
    return;
  }
  size_t g3 = g2 - 1572864;
  if (g3 < 262144) {
    float4 v = ((const float4*)outw)[g3];
    ushort4 o; o.x = f2bf(v.x); o.y = f2bf(v.y); o.z = f2bf(v.z); o.w = f2bf(v.w);
    ((ushort4*)outwb)[g3] = o;
  }
}

// ---------------- fused QKV GEMM: 128x128 tile + in-epilogue RoPE/scatter.
__global__ __launch_bounds__(256) void gemm_qkv(
    const u16* __restrict__ A, const u16* __restrict__ Bw,
    const float* __restrict__ cosb, const float* __restrict__ sinb,
    u16* __restrict__ qr, u16* __restrict__ kr, u16* __restrict__ vt) {
  __shared__ u16 As[128][64];
  __shared__ u16 Bs[128][64];
  const unsigned flat = blockIdx.x;
  const int bm = (flat >> 3) & 15;
  const int bn = ((flat >> 7) << 3) + (flat & 7);  // same bn -> same XCD
  const int tid = threadIdx.x;
  const int wave = tid >> 6, lane = tid & 63;
  const int quad = lane >> 4, l16 = lane & 15;
  const int wm = wave & 1, wn = wave >> 1;
  const int srow = lane >> 3, skc = (lane & 7) * 8;
  floatx4 acc[4][4];
#pragma unroll
  for (int i = 0; i < 4; i++)
#pragma unroll
    for (int j = 0; j < 4; j++) { acc[i][j][0] = 0.f; acc[i][j][1] = 0.f; acc[i][j][2] = 0.f; acc[i][j][3] = 0.f; }
  const u16* Abase = A + (size_t)(bm * 128) * 1024;
  const u16* Bbase = Bw + (size_t)(bn * 128) * 1024;
  for (int k0 = 0; k0 < 1024; k0 += 64) {
    __syncthreads();
#pragma unroll
    for (int i = 0; i < 4; i++) {
      int ch = wave * 4 + i;
      stage16(Abase + (size_t)(ch * 8 + srow) * 1024 + k0 + skc, &As[ch * 8][0], lane);
      stage16(Bbase + (size_t)(ch * 8 + srow) * 1024 + k0 + skc, &Bs[ch * 8][0], lane);
    }
    __syncthreads();
#pragma unroll
    for (int kf = 0; kf < 2; kf++) {
      short8 af[4], bf[4];
#pragma unroll
      for (int mi = 0; mi < 4; mi++)
        af[mi] = *(const short8*)(&As[wm * 64 + mi * 16 + l16][kf * 32 + quad * 8]);
#pragma unroll
      for (int ni = 0; ni < 4; ni++)
        bf[ni] = *(const short8*)(&Bs[wn * 64 + ni * 16 + l16][kf * 32 + quad * 8]);
#pragma unroll
      for (int mi = 0; mi < 4; mi++)
#pragma unroll
        for (int ni = 0; ni < 4; ni++)
          acc[mi][ni] = MFMA16(af[mi], bf[ni], acc[mi][ni]);
    }
  }
  // ---- fused epilogue (wave-uniform branches) ----
  const int f0 = bn * 128 + wn * 64;   // wave's feature base
  const int lay = f0 >> 11;
  const int r0 = f0 & 2047;            // multiple of 64 -> type/head uniform
  const int mrow0 = bm * 128 + wm * 64;
  if (r0 < 1024) {                     // ---- Q: RoPE(pos=t) * scale*log2e
    const int h = r0 >> 6;
#pragma unroll
    for (int mi = 0; mi < 4; mi++)
#pragma unroll
      for (int rr = 0; rr < 4; rr++) {
        int m = mrow0 + mi * 16 + quad * 4 + rr;
        int b = m >> 10, t = m & 1023;
        const float* cp = cosb + (size_t)t * 32;
        const float* sp = sinb + (size_t)t * 32;
        float c0 = cp[l16], s0 = sp[l16];
        float c1 = cp[16 + l16], s1 = sp[16 + l16];
        float x10 = acc[mi][0][rr], x20 = acc[mi][2][rr];
        float x11 = acc[mi][1][rr], x21 = acc[mi][3][rr];
        u16* row = qr + ((((size_t)lay * 2 + b) * 16 + h) * 1024 + t) * 64;
        row[l16]      = f2bf((x10 * c0 - x20 * s0) * QSCALE);
        row[16 + l16] = f2bf((x11 * c1 - x21 * s1) * QSCALE);
        row[32 + l16] = f2bf((x20 * c0 + x10 * s0) * QSCALE);
        row[48 + l16] = f2bf((x21 * c1 + x11 * s1) * QSCALE);
      }
  } else if (r0 < 1536) {              // ---- K: RoPE(pos=lay*1024+t)
    const int hk = (r0 - 1024) >> 6;
#pragma unroll
    for (int mi = 0; mi < 4; mi++)
#pragma unroll
      for (int rr = 0; rr < 4; rr++) {
        int m = mrow0 + mi * 16 + quad * 4 + rr;
        int b = m >> 10, t = m & 1023;
        int pos = lay * 1024 + t;
        const float* cp = cosb + (size_t)pos * 32;
        const float* sp = sinb + (size_t)pos * 32;
        float c0 = cp[l16], s0 = sp[l16];
        float c1 = cp[16 + l16], s1 = sp[16 + l16];
        float x10 = acc[mi][0][rr], x20 = acc[mi][2][rr];
        float x11 = acc[mi][1][rr], x21 = acc[mi][3][rr];
        u16* row = kr + (((size_t)(b * 8 + hk)) * 3072 + pos) * 64;
        row[l16]      = f2bf(x10 * c0 - x20 * s0);
        row[16 + l16] = f2bf(x11 * c1 - x21 * s1);
        row[32 + l16] = f2bf(x20 * c0 + x10 * s0);
        row[48 + l16] = f2bf(x21 * c1 + x11 * s1);
      }
  } else {                             // ---- V: transposed store [d][pos], 8B packs
    const int hv = (r0 - 1536) >> 6;
#pragma unroll
    for (int mi = 0; mi < 4; mi++) {
      int m0 = mrow0 + mi * 16 + quad * 4;
      int b = m0 >> 10;
      int pos0 = lay * 1024 + (m0 & 1023);
      u16* colbase = vt + ((size_t)(b * 8 + hv) * 64) * 3072 + pos0;
#pragma unroll
      for (int ni = 0; ni < 4; ni++) {
        int d = ni * 16 + l16;
        uint2 st;
        st.x = pack2bf(acc[mi][ni][0], acc[mi][ni][1]);
        st.y = pack2bf(acc[mi][ni][2], acc[mi][ni][3]);
        *(uint2*)(colbase + (size_t)d * 3072) = st;
      }
    }
  }
}

// ---------------- out-projection GEMM: 64x64 tile, double-buffered
// (proven in v14: ~5-6us total win; single barrier per K-step).
__global__ __launch_bounds__(256) void gemm_bt(
    const u16* __restrict__ A, const u16* __restrict__ Bw,
    float* __restrict__ C, int N, int K) {
  __shared__ u16 As[2][64][72];
  __shared__ u16 Bs[2][64][72];
  const int bm = blockIdx.x, bn = blockIdx.y;
  const int tid = threadIdx.x;
  const int wave = tid >> 6, lane = tid & 63;
  const int quad = lane >> 4, l16 = lane & 15;
  const int lr = tid >> 2, lc = (tid & 3) << 4;
  floatx4 acc[4];
#pragma unroll
  for (int i = 0; i < 4; i++) { acc[i][0] = 0.f; acc[i][1] = 0.f; acc[i][2] = 0.f; acc[i][3] = 0.f; }
  const u16* Arow = A + (size_t)(bm * 64 + lr) * K;
  const u16* Brow = Bw + (size_t)(bn * 64 + lr) * K;
  // prologue: tile 0 -> buf0; prefetch tile 1 into regs
  uint4 ra0 = *(const uint4*)(Arow + lc);
  uint4 ra1 = *(const uint4*)(Arow + lc + 8);
  uint4 rb0 = *(const uint4*)(Brow + lc);
  uint4 rb1 = *(const uint4*)(Brow + lc + 8);
  *(uint4*)(&As[0][lr][lc])     = ra0;
  *(uint4*)(&As[0][lr][lc + 8]) = ra1;
  *(uint4*)(&Bs[0][lr][lc])     = rb0;
  *(uint4*)(&Bs[0][lr][lc + 8]) = rb1;
  if (64 < K) {
    ra0 = *(const uint4*)(Arow + 64 + lc);
    ra1 = *(const uint4*)(Arow + 64 + lc + 8);
    rb0 = *(const uint4*)(Brow + 64 + lc);
    rb1 = *(const uint4*)(Brow + 64 + lc + 8);
  }
  int p = 0;
  for (int k0 = 0; k0 < K; k0 += 64, p ^= 1) {
    __syncthreads();   // buf[p] writes visible; prior reads of buf[p^1] done
    if (k0 + 64 < K) {  // write-late: next tile -> other buffer
      *(uint4*)(&As[p ^ 1][lr][lc])     = ra0;
      *(uint4*)(&As[p ^ 1][lr][lc + 8]) = ra1;
      *(uint4*)(&Bs[p ^ 1][lr][lc])     = rb0;
      *(uint4*)(&Bs[p ^ 1][lr][lc + 8]) = rb1;
      if (k0 + 128 < K) {
        ra0 = *(const uint4*)(Arow + k0 + 128 + lc);
        ra1 = *(const uint4*)(Arow + k0 + 128 + lc + 8);
        rb0 = *(const uint4*)(Brow + k0 + 128 + lc);
        rb1 = *(const uint4*)(Brow + k0 + 128 + lc + 8);
      }
    }
    const int mrow = wave * 16 + l16;
    short8 a0 = *(const short8*)(&As[p][mrow][quad * 8]);
    short8 a1 = *(const short8*)(&As[p][mrow][32 + quad * 8]);
#pragma unroll
    for (int ns = 0; ns < 4; ns++) {
      short8 b0 = *(const short8*)(&Bs[p][ns * 16 + l16][quad * 8]);
      short8 b1 = *(const short8*)(&Bs[p][ns * 16 + l16][32 + quad * 8]);
      acc[ns] = MFMA16(a0, b0, acc[ns]);
      acc[ns] = MFMA16(a1, b1, acc[ns]);
    }
  }
#pragma unroll
  for (int ns = 0; ns < 4; ns++)
#pragma unroll
    for (int r = 0; r < 4; r++) {
      int row = bm * 64 + wave * 16 + quad * 4 + r;
      int col = bn * 64 + ns * 16 + l16;
      C[(size_t)row * N + col] = acc[ns][r];
    }
}

// ---------------- attention FINAL: exact v8/v15 structure — the measured
// optimum of 12 variants (75-79us). Latency-bound equilibrium: barriers/2,
// conflicts/2, staging/2, work-10%, ILP x2, setprio, reg caps all measured
// null or negative. Further gains require the full 8-phase counted-vmcnt
// T-stack rewrite (guide §5.5), not incremental edits.
__global__ __launch_bounds__(512) void attn_final(
    const u16* __restrict__ qr, const u16* __restrict__ kr,
    const u16* __restrict__ vt, u16* __restrict__ obS,
    float* __restrict__ lbufp) {
  // layout (u16 units): Kt[2][32][72] at 0 (4608) | Vtt[2][64][40] at 4608 (5120)
  // epilogue: float scratch wave*320 floats aliased at base (after barrier)
  __shared__ __align__(16) u16 smem[9728];   // 19456 B
  u16* KtB = smem;
  u16* VtB = smem + 4608;
  const unsigned flat = blockIdx.x;
  const int xcd = (int)(flat & 7);
  const int m = (int)(flat >> 3);       // 0..95
  const int qtile = m / 12;             // 0..7 (non-pow2 scatter over CUs)
  const int g = m - qtile * 12;         // 0..11
  const int pid = g * 8 + xcd;          // 0..95 = (z,b,j); low bits keep XCD L2 locality
  const int z = pid >> 4;
  const int rb = pid & 15;
  const int b = rb >> 3, j = rb & 7;    // j = kv head (hk)
  const int lay = (z == 5) ? 0 : ((z == 0 || z == 4) ? 1 : 2);
  const int n = lay * 32 + qtile * 4 + 4;   // total 32-key tiles for this (lay,qtile)
  int kt0, kt1;
  if (lay == 0) { kt0 = 0; kt1 = n; }
  else if (lay == 1) { int hf = n >> 1; kt0 = (z == 0) ? 0 : hf; kt1 = (z == 0) ? hf : n; }
  else {
    int t1 = n / 3, t2 = (2 * n) / 3;
    kt0 = (z == 1) ? 0 : ((z == 2) ? t1 : t2);
    kt1 = (z == 1) ? t1 : ((z == 2) ? t2 : n);
  }
  const int maskkt = lay * 32 + qtile * 4;
  const int tid = threadIdx.x, wave = tid >> 6, lane = tid & 63;
  const int quad = lane >> 4, l16 = lane & 15;
  const int hw = wave >> 2, wq = wave & 3;   // head-half, wave-within-head
  const int h = j * 2 + hw;
  const int qeffbase = lay * 1024 + qtile * 128 + wq * 32;
  const u16* qpb = qr + ((((size_t)lay * 2 + b) * 16 + h) * 1024
                         + qtile * 128 + wq * 32 + l16) * 64 + quad * 8;
  short8 qf[2][2];
  qf[0][0] = *(const short8*)(qpb);
  qf[0][1] = *(const short8*)(qpb + 32);
  qf[1][0] = *(const short8*)(qpb + 1024);
  qf[1][1] = *(const short8*)(qpb + 1056);
  const s16x4 ones4 = {16256, 16256, 16256, 16256};
  floatx4 oacc[2][4];
#pragma unroll
  for (int nt = 0; nt < 2; nt++)
#pragma unroll
    for (int dt = 0; dt < 4; dt++) { oacc[nt][dt][0] = 0.f; oacc[nt][dt][1] = 0.f; oacc[nt][dt][2] = 0.f; oacc[nt][dt][3] = 0.f; }
  floatx4 lacc[2];
  lacc[0][0] = 0.f; lacc[0][1] = 0.f; lacc[0][2] = 0.f; lacc[0][3] = 0.f;
  lacc[1] = lacc[0];
  // staging: waves 0-3 (256 lanes) stage K tile (32x64), waves 4-7 stage V (64x32)
  const bool isK = (tid < 256);
  const int t2i = tid & 255;
  const int ksr = t2i >> 3, ksc = (t2i & 7) * 8;   // K: 8 lanes/row x 16B
  const int vdr = t2i >> 2, vdc = (t2i & 3) * 8;   // V: 4 lanes/row x 16B
  const u16* gp = isK
      ? kr + ((size_t)(b * 8 + j) * 3072 + kt0 * 32 + ksr) * 64 + ksc
      : vt + ((size_t)(b * 8 + j) * 64 + vdr) * 3072 + kt0 * 32 + vdc;
  const size_t gstep = isK ? 2048 : 32;
  u16* ld0 = isK ? &KtB[ksr * 72 + ksc] : &VtB[vdr * 40 + vdc];
  u16* ld1 = isK ? &KtB[2304 + ksr * 72 + ksc] : &VtB[2560 + vdr * 40 + vdc];
  // prologue: tile kt0 -> buf0; prefetch tile kt0+1 into regs
  uint4 gA = *(const uint4*)gp;
  *(uint4*)ld0 = gA;
  gp += gstep;
  if (kt0 + 1 < kt1) gA = *(const uint4*)gp;
  for (int kt = kt0; kt < kt1; kt++) {
    const int p = (kt - kt0) & 1;
    __syncthreads();   // buf[p] writes visible; prior reads of buf[p^1] done
    if (kt + 1 < kt1) {   // write-late: next tile -> other buffer, overlaps compute
      *(uint4*)(p ? ld0 : ld1) = gA;
      gp += gstep;
      if (kt + 2 < kt1) gA = *(const uint4*)gp;
    }
    const bool needmask = (kt >= maskkt);
    const u16* Ktp = &KtB[p * 2304];
    const u16* Vtp = &VtB[p * 2560];
    uint2 pk[2][2];  // [mt][nt], 4 bf16 each = keys quad*4..+3 of 16-key group mt
#pragma unroll
    for (int mt = 0; mt < 2; mt++) {
      short8 kfa = *(const short8*)(&Ktp[(mt * 16 + l16) * 72 + quad * 8]);
      short8 kfb = *(const short8*)(&Ktp[(mt * 16 + l16) * 72 + 32 + quad * 8]);
      const int keyb = kt * 32 + mt * 16 + quad * 4;
#pragma unroll
      for (int nt = 0; nt < 2; nt++) {
        floatx4 s; s[0] = 0.f; s[1] = 0.f; s[2] = 0.f; s[3] = 0.f;
        s = MFMA16(kfa, qf[nt][0], s);
        s = MFMA16(kfb, qf[nt][1], s);
        float p0 = EXP2(s[0]), p1 = EXP2(s[1]);
        float p2 = EXP2(s[2]), p3 = EXP2(s[3]);
        if (needmask) {
          int qpos = qeffbase + nt * 16 + l16;
          if (keyb + 0 > qpos) p0 = 0.f;
          if (keyb + 1 > qpos) p1 = 0.f;
          if (keyb + 2 > qpos) p2 = 0.f;
          if (keyb + 3 > qpos) p3 = 0.f;
        }
        pk[mt][nt].x = packbf(p0, p1);
        pk[mt][nt].y = packbf(p2, p3);
      }
    }
    s16x4 p0f0 = __builtin_bit_cast(s16x4, pk[0][0]);
    s16x4 p1f0 = __builtin_bit_cast(s16x4, pk[1][0]);
    s16x4 p0f1 = __builtin_bit_cast(s16x4, pk[0][1]);
    s16x4 p1f1 = __builtin_bit_cast(s16x4, pk[1][1]);
    lacc[0] = MFMAK16(ones4, p0f0, lacc[0]);
    lacc[0] = MFMAK16(ones4, p1f0, lacc[0]);
    lacc[1] = MFMAK16(ones4, p0f1, lacc[1]);
    lacc[1] = MFMAK16(ones4, p1f1, lacc[1]);
    // V fragments loaded per-dt: a[j] = V^T[d][k=quad*4+j]
#pragma unroll
    for (int dt = 0; dt < 4; dt++) {
      s16x4 v0 = *(const s16x4*)(&Vtp[(dt * 16 + l16) * 40 + quad * 4]);
      s16x4 v1 = *(const s16x4*)(&Vtp[(dt * 16 + l16) * 40 + 16 + quad * 4]);
      oacc[0][dt] = MFMAK16(v0, p0f0, oacc[0][dt]);
      oacc[0][dt] = MFMAK16(v1, p1f0, oacc[0][dt]);
      oacc[1][dt] = MFMAK16(v0, p0f1, oacc[1][dt]);
      oacc[1][dt] = MFMAK16(v1, p1f1, oacc[1][dt]);
    }
  }
  // epilogue: O^T (d,t) -> row-major [t][d] via per-wave scratch ALIASED on K/V
  __syncthreads();   // all waves done reading Kt/Vtt before scratch overwrite
  float* Pf = (float*)smem + wave * 320;   // 16x20 floats per wave
  const int tt = lane >> 2, dd = (lane & 3) << 2;
#pragma unroll
  for (int nt = 0; nt < 2; nt++) {
    int t = qtile * 128 + wq * 32 + nt * 16 + l16;
    if (quad == 0)
      lbufp[((size_t)z * 2048 + b * 1024 + t) * 16 + h] = lacc[nt][0];
    int t2 = qtile * 128 + wq * 32 + nt * 16 + tt;
    u16* orow = obS + ((size_t)(z * 2 + b) * 1024 + t2) * 1024 + h * 64 + dd;
#pragma unroll
    for (int dt = 0; dt < 4; dt++) {
      *(floatx4*)(&Pf[l16 * 20 + quad * 4]) = oacc[nt][dt];   // [t][d] tile
      floatx4 val = *(const floatx4*)(&Pf[tt * 20 + dd]);     // wave in-order
      uint2 st; st.x = pack2bf(val[0], val[1]); st.y = pack2bf(val[2], val[3]);
      *(uint2*)(orow + dt * 16) = st;
    }
  }
}

// ---------------- fused norm: merged 3-layer reduction.
__device__ __forceinline__ void block_sum3(float& v0, float& v1, float& v2,
                                           float* red) {
#pragma unroll
  for (int s = 32; s >= 1; s >>= 1) {
    v0 += __shfl_xor(v0, s);
    v1 += __shfl_xor(v1, s);
    v2 += __shfl_xor(v2, s);
  }
  __syncthreads();
  if ((threadIdx.x & 63) == 0) {
    int w = threadIdx.x >> 6;
    red[w * 3 + 0] = v0; red[w * 3 + 1] = v1; red[w * 3 + 2] = v2;
  }
  __syncthreads();
  v0 = red[0] + red[3] + red[6] + red[9];
  v1 = red[1] + red[4] + red[7] + red[10];
  v2 = red[2] + red[5] + red[8] + red[11];
}

__device__ __forceinline__ float block_sum(float v, float* red) {
  v += __shfl_xor(v, 32); v += __shfl_xor(v, 16); v += __shfl_xor(v, 8);
  v += __shfl_xor(v, 4);  v += __shfl_xor(v, 2);  v += __shfl_xor(v, 1);
  __syncthreads();
  if ((threadIdx.x & 63) == 0) red[threadIdx.x >> 6] = v;
  __syncthreads();
  return red[0] + red[1] + red[2] + red[3];
}

__device__ __forceinline__ void addslot(const u16* __restrict__ obS,
    const float* __restrict__ lbufp, int row, int tid, int z,
    float o[4], float& ls) {
  uint2 v = ((const uint2*)(obS + ((size_t)z * 2048 + row) * 1024))[tid];
  o[0] += bf2f((u16)(v.x & 0xffff)); o[1] += bf2f((u16)(v.x >> 16));
  o[2] += bf2f((u16)(v.y & 0xffff)); o[3] += bf2f((u16)(v.y >> 16));
  ls += lbufp[((size_t)z * 2048 + row) * 16 + (tid >> 4)];
}

__global__ __launch_bounds__(256) void fused_norm(
    const u16* __restrict__ obS, const float* __restrict__ lbufp,
    const float* __restrict__ x, const float* __restrict__ lnw,
    const float* __restrict__ lwbuf, const float* __restrict__ flnw,
    const float* __restrict__ alphap, u16* __restrict__ y) {
  __shared__ float red[12];
  const int row = blockIdx.x, tid = threadIdx.x;  // row = b*1024+t
  // layer -> slots: l0 = {5}, l1 = {0,4}, l2 = {1,2,3}
  float q0[4] = {0.f, 0.f, 0.f, 0.f};
  float q1[4] = {0.f, 0.f, 0.f, 0.f};
  float q2[4] = {0.f, 0.f, 0.f, 0.f};
  float ls0 = 0.f, ls1 = 0.f, ls2 = 0.f;
  addslot(obS, lbufp, row, tid, 5, q0, ls0);
  addslot(obS, lbufp, row, tid, 0, q1, ls1);
  addslot(obS, lbufp, row, tid, 4, q1, ls1);
  addslot(obS, lbufp, row, tid, 1, q2, ls2);
  addslot(obS, lbufp, row, tid, 2, q2, ls2);
  addslot(obS, lbufp, row, tid, 3, q2, ls2);
  const float i0 = 1.f / ls0, i1 = 1.f / ls1, i2 = 1.f / ls2;
  float u0[4], u1[4], u2[4];
#pragma unroll
  for (int k = 0; k < 4; k++) { u0[k] = q0[k] * i0; u1[k] = q1[k] * i1; u2[k] = q2[k] * i2; }
  float ss0 = u0[0]*u0[0] + u0[1]*u0[1] + u0[2]*u0[2] + u0[3]*u0[3];
  float ss1 = u1[0]*u1[0] + u1[1]*u1[1] + u1[2]*u1[2] + u1[3]*u1[3];
  float ss2 = u2[0]*u2[0] + u2[1]*u2[1] + u2[2]*u2[2] + u2[3]*u2[3];
  block_sum3(ss0, ss1, ss2, red);
  const float r0 = rsqrtf(ss0 * (1.f / 1024.f) + 1e-5f) * lwbuf[0];
  const float r1 = rsqrtf(ss1 * (1.f / 1024.f) + 1e-5f) * lwbuf[1];
  const float r2 = rsqrtf(ss2 * (1.f / 1024.f) + 1e-5f) * lwbuf[2];
  float4 w0 = ((const float4*)(lnw))[tid];
  float4 w1 = ((const float4*)(lnw + 1024))[tid];
  float4 w2 = ((const float4*)(lnw + 2048))[tid];
  float a[4];
  a[0] = u0[0]*r0*w0.x + u1[0]*r1*w1.x + u2[0]*r2*w2.x;
  a[1] = u0[1]*r0*w0.y + u1[1]*r1*w1.y + u2[1]*r2*w2.y;
  a[2] = u0[2]*r0*w0.z + u1[2]*r1*w1.z + u2[2]*r2*w2.z;
  a[3] = u0[3]*r0*w0.w + u1[3]*r1*w1.w + u2[3]*r2*w2.w;
  const float aa = alphap[0];
  float4 xv = ((const float4*)(x + (size_t)row * 1024))[tid];
  float v0 = a[0] + aa * xv.x, v1 = a[1] + aa * xv.y;
  float v2 = a[2] + aa * xv.z, v3 = a[3] + aa * xv.w;
  float ss = v0 * v0 + v1 * v1 + v2 * v2 + v3 * v3;
  ss = block_sum(ss, red);
  float rstd = rsqrtf(ss * (1.f / 1024.f) + 1e-5f);
  float4 fw = ((const float4*)flnw)[tid];
  ushort4 o;
  o.x = f2bf(v0 * rstd * fw.x); o.y = f2bf(v1 * rstd * fw.y);
  o.z = f2bf(v2 * rstd * fw.z); o.w = f2bf(v3 * rstd * fw.w);
  ((ushort4*)(y + (size_t)row * 1024))[tid] = o;
}

extern "C" void kernel_launch(void* const* d_in, const int* in_sizes, int n_in,
                              void* d_out, int out_size, void* d_ws, size_t ws_size,
                              hipStream_t stream) {
  const float* x     = (const float*)d_in[0];
  const float* cosb  = (const float*)d_in[1];
  const float* sinb  = (const float*)d_in[2];
  const float* qw    = (const float*)d_in[3];
  const float* kw    = (const float*)d_in[4];
  const float* vw    = (const float*)d_in[5];
  const float* lnw   = (const float*)d_in[6];
  const float* lam   = (const float*)d_in[7];
  const float* outw  = (const float*)d_in[8];
  const float* flnw  = (const float*)d_in[9];
  const float* alphap= (const float*)d_in[10];
  float* out = (float*)d_out;
  char* ws = (char*)d_ws;
  // workspace (~57.4 MB). Region [0,24M) is time-shared:
  //   phase 1 (prep/gemm_qkv): xb [0,4M) + wcat [4M,16M)
  //   phase 2 (attn/fused_norm): obS [0,24M)  bf16 [z][b][t][h*64+d]
  u16*   xb    = (u16*)  (ws + 0);          //  4 MB
  u16*   wcat  = (u16*)  (ws + 4194304);    // 12 MB
  u16*   obS   = (u16*)  (ws + 0);          // 24 MB (phase 2)
  u16*   outwb = (u16*)  (ws + 25165824);   //  2 MB
  float* lwbuf = (float*)(ws + 27262976);   //  1 KB
  u16*   qr    = (u16*)  (ws + 27264000);   // 12 MB  [3][2][16][1024][64]
  u16*   kr    = (u16*)  (ws + 39846912);   //  6 MB  [2][8][3072][64]
  u16*   vt    = (u16*)  (ws + 46138368);   //  6 MB  [2][8][64][3072]
  float* lbufp = (float*)(ws + 52429824);   // 768 KB [6][2048][16]
  u16*   yb    = (u16*)  (ws + 53216256);   //  4 MB

  prep_kernel<<<9216, 256, 0, stream>>>(x, qw, kw, vw, outw, lam, xb, wcat, outwb, lwbuf);
  gemm_qkv<<<768, 256, 0, stream>>>(xb, wcat, cosb, sinb, qr, kr, vt);
  attn_final<<<768, 512, 0, stream>>>(qr, kr, vt, obS, lbufp);
  fused_norm<<<2048, 256, 0, stream>>>(obS, lbufp, x, lnw, lwbuf, flnw, alphap, yb);
  gemm_bt<<<dim3(32, 16), 256, 0, stream>>>(yb, outwb, out, 1024, 1024);
}